// Round 5
// baseline (1022.720 us; speedup 1.0000x reference)
//
#include <hip/hip_runtime.h>
#include <hip/hip_bf16.h>
#include <cstdint>

typedef uint16_t u16;
typedef __attribute__((ext_vector_type(8))) short short8;
typedef __attribute__((ext_vector_type(4))) float floatx4;

#define S_LEN 512
#define N_TOT 3584              // 7*512
#define HG_ROW 8388608          // 512*32*512 : flat base of row S in (S+1,B,H)
#define CT_BASE 8404992         // 513*32*512 : c_t base in out (f32 elements)

__device__ __forceinline__ uint32_t pk2(float a, float b) {
  __hip_bfloat162 t = __float22bfloat162_rn(float2{a, b});
  return *(uint32_t*)&t;
}
__device__ __forceinline__ uint4 pack8f(const float* p) {
  const float4 x = *(const float4*)p;
  const float4 y = *(const float4*)(p + 4);
  uint4 r;
  r.x = pk2(x.x, x.y); r.y = pk2(x.z, x.w);
  r.z = pk2(y.x, y.y); r.w = pk2(y.z, y.w);
  return r;
}
__device__ __forceinline__ float sigm(float x) { return 1.f / (1.f + __expf(-x)); }
__device__ __forceinline__ float tanh_(float x) { return 2.f / (1.f + __expf(-2.f * x)) - 1.f; }

// seq_lens may be int32 or int64 (values in [1,512]): int64 => p[1]==0 (high word).
__device__ __forceinline__ int sl_stride(const int* p) { return (p[1] == 0) ? 2 : 1; }

// ---- h_hat[b,h] = (1/512) * sum_{s<len} h0[s,b,h] ----
__global__ void k_hhat(const float* __restrict__ h0, const int* __restrict__ seq_lens,
                       float* __restrict__ hhat) {
  int id = blockIdx.x * 256 + threadIdx.x;       // 16384 = b*512+h
  int b = id >> 9, h = id & 511;
  int len = seq_lens[b * sl_stride(seq_lens)];
  const float* p = h0 + (size_t)b * 512 + h;
  float s = 0.f;
  for (int t = 0; t < len; ++t) s += p[(size_t)t * 16384];
  hhat[id] = s * (1.f / 512.f);
}

// ---- small matmuls: sg0(fg pre), sg2(og pre), a1 (h_g1@Sw1^T + Sb1), Vb[g,b,n] ----
__global__ void k_small(const float* __restrict__ h0, const float* __restrict__ Sw,
                        const float* __restrict__ Su, const float* __restrict__ Sb,
                        const float* __restrict__ Wv, const float* __restrict__ Wb,
                        const float* __restrict__ hhat,
                        float* __restrict__ sg0, float* __restrict__ sg2,
                        float* __restrict__ a1v, float* __restrict__ Vb) {
  int id = blockIdx.x * 256 + threadIdx.x;       // < 163840
  const float* hg1base = h0 + (size_t)HG_ROW;
  if (id < 49152) {
    int job = id >> 14;                          // 0:fg 1:og 2:fi-a1
    int r = id & 16383;
    int b = r >> 9, hh = r & 511;
    int widx = (job == 0) ? 0 : (job == 1) ? 2 : 1;
    const float* swrow = Sw + ((size_t)widx * 512 + hh) * 512;
    const float* hg1 = hg1base + (size_t)b * 512;
    float acc = Sb[widx * 512 + hh];
    for (int k = 0; k < 512; ++k) acc += hg1[k] * swrow[k];
    if (job == 2) { a1v[r] = acc; }
    else {
      const float* surow = Su + ((size_t)widx * 512 + hh) * 512;
      const float* hb = hhat + b * 512;
      for (int k = 0; k < 512; ++k) acc += hb[k] * surow[k];
      if (job == 0) sg0[r] = acc; else sg2[r] = acc;
    }
  } else {
    int r = id - 49152;                          // Vb: 7*16384
    int g = r >> 14; int r2 = r & 16383;
    int b = r2 >> 9, n = r2 & 511;
    const float* wv = Wv + ((size_t)g * 512 + n) * 512;
    const float* hg1 = hg1base + (size_t)b * 512;
    float acc = Wb[g * 512 + n];
    for (int k = 0; k < 512; ++k) acc += hg1[k] * wv[k];
    Vb[((size_t)g * 32 + b) * 512 + n] = acc;
  }
}

__global__ void k_zero(float* __restrict__ p, int n) {
  int i = blockIdx.x * 256 + threadIdx.x;
  if (i < n) p[i] = 0.f;
}

// ---- bf16 MFMA GEMM over f32 inputs (inline cvt), in-kernel A masking/shifting ----
// C[m,n] = sum_t sum_k A_t[m+aoff,k] * B_t[brow0+n, bcol+k]
struct GemmSrc {
  const float* a[4]; // row length 512 (h0 rows 0..16383, or seqs)
  const float* b[4];
  int aoff[4];       // A row shift (window): -32 / 0 / +32
  int amask[4];      // apply seq_lens mask to A rows?
  int bld[4];
  int brow0[4];      // B row offset
  int bcol[4];       // B column offset
};

__global__ __launch_bounds__(256)
void gemm_kernel(GemmSrc ga, const int* __restrict__ seq_lens,
                 float* __restrict__ C, int ldc, int nblk, int m0base) {
  __shared__ __align__(16) u16 sA[128 * 32];
  __shared__ __align__(16) u16 sB[128 * 32];
  __shared__ int sLen[32];
  const int tid = threadIdx.x;
  const int wave = tid >> 6, lane = tid & 63;
  const int wr = wave >> 1, wc = wave & 1;
  const int lhi = lane >> 4, llo = lane & 15;
  const int m0 = blockIdx.y * 128;
  const int n0 = blockIdx.x * 128;

  if (tid < 32) sLen[tid] = seq_lens[tid * sl_stride(seq_lens)];
  __syncthreads();

  floatx4 acc[4][4];
#pragma unroll
  for (int i = 0; i < 4; ++i)
#pragma unroll
    for (int j = 0; j < 4; ++j) acc[i][j] = floatx4{0.f, 0.f, 0.f, 0.f};

  for (int t = 0; t < nblk; ++t) {
    const int bld = ga.bld[t];
    const float* abase = ga.a[t];
    const float* bbase = ga.b[t];
    const int aoff = ga.aoff[t], amask = ga.amask[t];
    const int brow0 = ga.brow0[t], bcol = ga.bcol[t];
#pragma unroll 1
    for (int kk = 0; kk < 16; ++kk) {
      const int kl = kk * 32;
      uint4 va[2], vb[2];
#pragma unroll
      for (int i = 0; i < 2; ++i) {
        int c = tid + 256 * i;
        int row = c >> 2, col = (c & 3) * 8 + kl;
        int gr = m0base + m0 + row + aoff;
        bool av = (unsigned)gr < 16384u;
        if (av && amask) av = ((gr >> 5) < sLen[gr & 31]);
        va[i] = av ? pack8f(abase + (size_t)gr * 512 + col) : make_uint4(0u, 0u, 0u, 0u);
        vb[i] = pack8f(bbase + (size_t)(brow0 + n0 + row) * bld + bcol + col);
      }
      __syncthreads();                           // prior iter's LDS reads done
#pragma unroll
      for (int i = 0; i < 2; ++i) {
        int c = tid + 256 * i;
        *(uint4*)(sA + c * 8) = va[i];
        *(uint4*)(sB + c * 8) = vb[i];
      }
      __syncthreads();
      short8 af[4], bf[4];
#pragma unroll
      for (int i = 0; i < 4; ++i) {
        af[i] = *(const short8*)(sA + (wr * 64 + i * 16 + llo) * 32 + lhi * 8);
        bf[i] = *(const short8*)(sB + (wc * 64 + i * 16 + llo) * 32 + lhi * 8);
      }
#pragma unroll
      for (int i = 0; i < 4; ++i)
#pragma unroll
        for (int j = 0; j < 4; ++j)
          acc[i][j] = __builtin_amdgcn_mfma_f32_16x16x32_bf16(af[i], bf[j], acc[i][j], 0, 0, 0);
    }
  }

  const int rb = m0 + wr * 64 + lhi * 4;
  const int cb = n0 + wc * 64 + llo;
#pragma unroll
  for (int i = 0; i < 4; ++i)
#pragma unroll
    for (int j = 0; j < 4; ++j)
#pragma unroll
      for (int r = 0; r < 4; ++r)
        C[(size_t)(rb + i * 16 + r) * ldc + (cb + j * 16)] = acc[i][j][r];
}

// ---- fi softmax-weighted reduction over s (chunked partials + atomics) ----
__global__ void k_fireduce(const float* __restrict__ Cfi, const float* __restrict__ a1v,
                           const float* __restrict__ c0, const int* __restrict__ seq_lens,
                           float* __restrict__ denom, float* __restrict__ cacc,
                           int sbase, int send) {
  int id = blockIdx.x * 256 + threadIdx.x;       // b*512+h
  int b = id >> 9, h = id & 511;
  int len = seq_lens[b * sl_stride(seq_lens)];
  int lim = (send < len) ? send : len;
  int s0 = sbase + blockIdx.y * 64;
  if (s0 >= lim) return;
  int s1 = (s0 + 64 < lim) ? s0 + 64 : lim;
  float a = a1v[id];
  float d = 0.f, ca = 0.f;
  for (int s = s0; s < s1; ++s) {
    size_t m = (size_t)(s * 32 + b);
    size_t ml = (size_t)((s - sbase) * 32 + b);
    float e = __expf(sigm(Cfi[ml * 512 + h] + a));
    d += e;
    ca += e * c0[m * 512 + h];
  }
  atomicAdd(&denom[id], d);
  atomicAdd(&cacc[id], ca);
}

// ---- global cell: c_g, h_g → out row S ----
__global__ void k_global(const float* __restrict__ sg0, const float* __restrict__ sg2,
                         const float* __restrict__ c0, const float* __restrict__ denom,
                         const float* __restrict__ cacc, float* __restrict__ out) {
  int id = blockIdx.x * 256 + threadIdx.x;       // 16384
  float fg = sigm(sg0[id]);
  float og = sigm(sg2[id]);
  float cg1 = c0[(size_t)HG_ROW + id];
  float dn = denom[id];
  float cg = fg * cg1 + cacc[id] / (dn > 0.f ? dn : 1.f);
  float hg = og * tanh_(cg);
  out[(size_t)HG_ROW + id] = hg;
  out[(size_t)CT_BASE + HG_ROW + id] = cg;
}

// ---- window epilogue: gates softmax-5, c_w, h_w ----
__global__ void k_epilogue(const float* __restrict__ Cch, const float* __restrict__ Vb,
                           const float* __restrict__ c0, const int* __restrict__ seq_lens,
                           float* __restrict__ out, int mbase) {
  int idx = blockIdx.x * 256 + threadIdx.x;      // chunk-local (m,h)
  int ml = idx >> 9, h = idx & 511;
  int mg = mbase + ml;
  int s = mg >> 5, b = mg & 31;
  int len = seq_lens[b * sl_stride(seq_lens)];
  float pre[7];
#pragma unroll
  for (int g = 0; g < 7; ++g)
    pre[g] = Cch[(size_t)ml * N_TOT + g * 512 + h] + Vb[(size_t)(g * 32 + b) * 512 + h];
  float i_ = sigm(pre[0]);
  float l_ = sigm(pre[1]);
  float r_ = sigm(pre[2]);
  float f_ = sigm(pre[3]);
  float sg = sigm(pre[4]);
  float o_ = sigm(pre[5]);
  float u_ = tanh_(pre[6]);
  float el = __expf(l_), ef = __expf(f_), er = __expf(r_), es = __expf(sg), ei = __expf(i_);
  float inv = 1.f / (el + ef + er + es + ei);
  float cw = 0.f;
  if (s < len) {
    float cl = (s >= 1) ? c0[(size_t)(mg - 32) * 512 + h] : 0.f;
    float cc = c0[(size_t)mg * 512 + h];
    float cr = (s + 1 < S_LEN && s + 1 < len) ? c0[(size_t)(mg + 32) * 512 + h] : 0.f;
    float cg1 = c0[(size_t)HG_ROW + b * 512 + h];
    cw = (el * cl + ef * cc + er * cr + es * cg1 + ei * u_) * inv;
  }
  float hw = o_ * tanh_(cw);
  size_t oi = (size_t)mg * 512 + h;
  out[oi] = hw;
  out[(size_t)CT_BASE + oi] = cw;
}

extern "C" void kernel_launch(void* const* d_in, const int* in_sizes, int n_in,
                              void* d_out, int out_size, void* d_ws, size_t ws_size,
                              hipStream_t stream) {
  const float* seqs = (const float*)d_in[0];
  const int* seq_lens = (const int*)d_in[1];
  const float* h0 = (const float*)d_in[2];
  const float* c0 = (const float*)d_in[3];
  const float* Ww = (const float*)d_in[4];
  const float* Wu = (const float*)d_in[5];
  const float* Wv = (const float*)d_in[6];
  const float* Wb = (const float*)d_in[7];
  const float* Sw = (const float*)d_in[8];
  const float* Su = (const float*)d_in[9];
  const float* Sb = (const float*)d_in[10];
  float* out = (float*)d_out;

  // ---- workspace: small fixed buffers (~852 KB) + adaptive C chunk ----
  char* ws = (char*)d_ws;
  size_t off = 0;
  float* hhat = (float*)(ws + off); off += 16384 * 4;
  float* sg0  = (float*)(ws + off); off += 16384 * 4;
  float* sg2  = (float*)(ws + off); off += 16384 * 4;
  float* a1v  = (float*)(ws + off); off += 16384 * 4;
  float* Vb   = (float*)(ws + off); off += (size_t)7 * 16384 * 4;
  float* denom = (float*)(ws + off); off += 16384 * 4;
  float* cacc  = (float*)(ws + off); off += 16384 * 4;   // denom+cacc adjacent
  float* Cbig = (float*)(ws + off);

  size_t avail = (ws_size > off) ? (ws_size - off) : 0;
  int chunk_rows = 128;                                   // pow2 divisor of 16384
  for (int cr = 4096; cr >= 128; cr >>= 1)
    if ((size_t)cr * N_TOT * 4 <= avail) { chunk_rows = cr; break; }
  int fi_rows = 4 * chunk_rows;
  if (fi_rows > 16384) fi_rows = 16384;

  k_hhat<<<64, 256, 0, stream>>>(h0, seq_lens, hhat);
  k_small<<<640, 256, 0, stream>>>(h0, Sw, Su, Sb, Wv, Wb, hhat, sg0, sg2, a1v, Vb);
  k_zero<<<128, 256, 0, stream>>>(denom, 32768);          // denom + cacc

  // fi GEMM (16384 x 512) = h_w1 @ Su[1]^T, chunked over rows
  GemmSrc gfi;
  for (int i = 0; i < 4; ++i) {
    gfi.a[i] = h0; gfi.aoff[i] = 0; gfi.amask[i] = 1;
    gfi.b[i] = Su; gfi.bld[i] = 512; gfi.brow0[i] = 512; gfi.bcol[i] = 0;
  }
  for (int fb = 0; fb < 16384; fb += fi_rows) {
    gemm_kernel<<<dim3(4, fi_rows / 128), 256, 0, stream>>>(gfi, seq_lens, Cbig, 512, 1, fb);
    int sbase = fb / 32, scnt = fi_rows / 32;
    k_fireduce<<<dim3(64, (scnt + 63) / 64), 256, 0, stream>>>(
        Cbig, a1v, c0, seq_lens, denom, cacc, sbase, sbase + scnt);
  }
  k_global<<<64, 256, 0, stream>>>(sg0, sg2, c0, denom, cacc, out);

  // main GEMM: K-blocks = {h_w1[s-1], h_w1[s], h_w1[s+1], seqs} x {Ww col-slices, Wu}
  GemmSrc gm;
  gm.a[0] = h0;   gm.aoff[0] = -32; gm.amask[0] = 1;
  gm.a[1] = h0;   gm.aoff[1] = 0;   gm.amask[1] = 1;
  gm.a[2] = h0;   gm.aoff[2] = 32;  gm.amask[2] = 1;
  gm.a[3] = seqs; gm.aoff[3] = 0;   gm.amask[3] = 0;
  gm.b[0] = Ww; gm.b[1] = Ww; gm.b[2] = Ww; gm.b[3] = Wu;
  gm.bld[0] = gm.bld[1] = gm.bld[2] = 1536; gm.bld[3] = 512;
  gm.brow0[0] = gm.brow0[1] = gm.brow0[2] = gm.brow0[3] = 0;
  gm.bcol[0] = 0; gm.bcol[1] = 512; gm.bcol[2] = 1024; gm.bcol[3] = 0;
  for (int mb = 0; mb < 16384; mb += chunk_rows) {
    gemm_kernel<<<dim3(28, chunk_rows / 128), 256, 0, stream>>>(gm, seq_lens, Cbig, N_TOT, 4, mb);
    k_epilogue<<<chunk_rows * 2, 256, 0, stream>>>(Cbig, Vb, c0, seq_lens, out, mb);
  }
}

// Round 6
// 630.628 us; speedup vs baseline: 1.6217x; 1.6217x over previous
//
#include <hip/hip_runtime.h>
#include <hip/hip_bf16.h>
#include <cstdint>

typedef uint16_t u16;
typedef __attribute__((ext_vector_type(8))) short short8;
typedef __attribute__((ext_vector_type(4))) float floatx4;

#define S_LEN 512
#define N_TOT 3584              // 7*512
#define HG_ROW 8388608          // 512*32*512 : flat base of row S in (S+1,B,H)
#define CT_BASE 8404992         // 513*32*512 : c_t base in out (f32 elements)

__device__ __forceinline__ float b2f(u16 u) {
  union { uint32_t i; float f; } v; v.i = ((uint32_t)u) << 16; return v.f;
}
__device__ __forceinline__ uint32_t pk2(float a, float b) {
  __hip_bfloat162 t = __float22bfloat162_rn(float2{a, b});
  return *(uint32_t*)&t;
}
__device__ __forceinline__ uint4 pack8f(const float* p) {
  const float4 x = *(const float4*)p;
  const float4 y = *(const float4*)(p + 4);
  uint4 r;
  r.x = pk2(x.x, x.y); r.y = pk2(x.z, x.w);
  r.z = pk2(y.x, y.y); r.w = pk2(y.z, y.w);
  return r;
}
__device__ __forceinline__ float sigm(float x) { return 1.f / (1.f + __expf(-x)); }
__device__ __forceinline__ float tanh_(float x) { return 2.f / (1.f + __expf(-2.f * x)) - 1.f; }
__device__ __forceinline__ int sl_stride(const int* p) { return (p[1] == 0) ? 2 : 1; }

__device__ __forceinline__ void gl_lds16(const void* g, void* l) {
  __builtin_amdgcn_global_load_lds((const __attribute__((address_space(1))) uint32_t*)g,
                                   (__attribute__((address_space(3))) uint32_t*)l, 16, 0, 0);
}

// ---- prep: hpad = [32 zero | masked bf16(h0[:-1]) | 32 zero] rows, row=(s*32+b)+32 ----
__global__ void prep_hpad(const float* __restrict__ h0, const int* __restrict__ seq_lens,
                          u16* __restrict__ hpad) {
  int i = blockIdx.x * 256 + threadIdx.x;        // 16448*64 groups of 8
  int row = i >> 6, cb = (i & 63) * 8;
  uint4 v = make_uint4(0u, 0u, 0u, 0u);
  if (row >= 32 && row < 16416) {
    int m = row - 32;
    if (((m >> 5)) < seq_lens[(m & 31) * sl_stride(seq_lens)])
      v = pack8f(h0 + (size_t)m * 512 + cb);
  }
  *(uint4*)(hpad + (size_t)row * 512 + cb) = v;
}

// ---- prep: seqs f32 -> bf16 ----
__global__ void prep_seqs(const float* __restrict__ seqs, u16* __restrict__ dst) {
  int i = blockIdx.x * 256 + threadIdx.x;        // 16384*64 groups
  size_t o = (size_t)i * 8;
  *(uint4*)(dst + o) = pack8f(seqs + o);
}

// ---- prep: Bcat[n][0:1536]=Ww[g,h,:], [1536:2048]=Wu[g,h,:]  (n=g*512+h), bf16 ----
__global__ void prep_bcat(const float* __restrict__ Ww, const float* __restrict__ Wu,
                          u16* __restrict__ Bcat) {
  int i = blockIdx.x * 256 + threadIdx.x;        // 3584*256 groups
  int n = i >> 8, col = (i & 255) * 8;
  const float* src = (col < 1536) ? Ww + (size_t)n * 1536 + col
                                  : Wu + (size_t)n * 512 + (col - 1536);
  *(uint4*)(Bcat + (size_t)n * 2048 + col) = pack8f(src);
}

// ---- prep: Bfi = bf16(Su[1]) ----
__global__ void prep_bfi(const float* __restrict__ Su, u16* __restrict__ Bfi) {
  int i = blockIdx.x * 256 + threadIdx.x;        // 512*64 groups
  size_t o = (size_t)i * 8;
  *(uint4*)(Bfi + o) = pack8f(Su + 262144 + o);
}

__global__ void k_zero(float* __restrict__ p, int n) {
  int i = blockIdx.x * 256 + threadIdx.x;
  if (i < n) p[i] = 0.f;
}

// ---- h_hat accumulation: parallel over s, atomics (hpad already masked) ----
__global__ void k_hhat(const u16* __restrict__ hpad, float* __restrict__ hhat) {
  int id = blockIdx.x * 256 + threadIdx.x;       // 16384 = b*512+h
  int b = id >> 9, h = id & 511;
  int s0 = blockIdx.y * 32;
  const u16* p = hpad + (size_t)(32 + s0 * 32 + b) * 512 + h;
  float s = 0.f;
#pragma unroll 4
  for (int i = 0; i < 32; ++i) s += b2f(p[(size_t)i * 16384]);
  atomicAdd(hhat + id, s * (1.f / 512.f));
}

// ---- small matmuls, wave-per-output, lane-split K=512, coalesced ----
// o<16384: sg0 ; <32768: sg2 ; <49152: a1v ; else Vb[g,b,n]
__global__ void k_small(const float* __restrict__ h0, const float* __restrict__ Sw,
                        const float* __restrict__ Su, const float* __restrict__ Sb,
                        const float* __restrict__ Wv, const float* __restrict__ Wb,
                        const float* __restrict__ hhat,
                        float* __restrict__ sg0, float* __restrict__ sg2,
                        float* __restrict__ a1v, float* __restrict__ Vb) {
  int o = blockIdx.x * 4 + (threadIdx.x >> 6);   // wave id = output id (163840)
  int lane = threadIdx.x & 63;
  int k0 = lane * 8;
  const float* hg1base = h0 + (size_t)HG_ROW;
  float acc = 0.f;
  float bias;
  float* dst;
  if (o < 49152) {
    int job = o >> 14, r = o & 16383;
    int b = r >> 9, hh = r & 511;
    int widx = (job == 0) ? 0 : (job == 1) ? 2 : 1;
    const float* ar = hg1base + (size_t)b * 512 + k0;
    const float* br = Sw + ((size_t)widx * 512 + hh) * 512 + k0;
    float4 a0 = *(const float4*)ar, a1 = *(const float4*)(ar + 4);
    float4 b0 = *(const float4*)br, b1 = *(const float4*)(br + 4);
    acc = a0.x*b0.x + a0.y*b0.y + a0.z*b0.z + a0.w*b0.w
        + a1.x*b1.x + a1.y*b1.y + a1.z*b1.z + a1.w*b1.w;
    if (job != 2) {
      const float* hr = hhat + (size_t)b * 512 + k0;
      const float* ur = Su + ((size_t)widx * 512 + hh) * 512 + k0;
      float4 h0v = *(const float4*)hr, h1v = *(const float4*)(hr + 4);
      float4 u0 = *(const float4*)ur, u1 = *(const float4*)(ur + 4);
      acc += h0v.x*u0.x + h0v.y*u0.y + h0v.z*u0.z + h0v.w*u0.w
           + h1v.x*u1.x + h1v.y*u1.y + h1v.z*u1.z + h1v.w*u1.w;
    }
    bias = Sb[widx * 512 + hh];
    dst = (job == 0) ? sg0 + r : (job == 1) ? sg2 + r : a1v + r;
  } else {
    int r = o - 49152;                           // 7*16384
    int g = r >> 14, r2 = r & 16383;
    int b = r2 >> 9, n = r2 & 511;
    const float* ar = hg1base + (size_t)b * 512 + k0;
    const float* br = Wv + ((size_t)g * 512 + n) * 512 + k0;
    float4 a0 = *(const float4*)ar, a1 = *(const float4*)(ar + 4);
    float4 b0 = *(const float4*)br, b1 = *(const float4*)(br + 4);
    acc = a0.x*b0.x + a0.y*b0.y + a0.z*b0.z + a0.w*b0.w
        + a1.x*b1.x + a1.y*b1.y + a1.z*b1.z + a1.w*b1.w;
    bias = Wb[g * 512 + n];
    dst = Vb + ((size_t)g * 32 + b) * 512 + n;
  }
#pragma unroll
  for (int off2 = 32; off2 > 0; off2 >>= 1) acc += __shfl_down(acc, off2);
  if (lane == 0) *dst = acc + bias;
}

// ---- m97-style bf16 GEMM: C[m,n] = sum_t sum_k A_t[m,k]*B_t[n, bcol+k] ----
struct GemmSrc {
  const u16* a[4];   // bf16, row length 512
  const u16* b[4];   // bf16, row length bld[t]
  int bld[4];
  int bcol[4];
};

__global__ __launch_bounds__(256)
void gemm_kernel(GemmSrc ga, float* __restrict__ C, int ldc, int nblk, int m0base) {
  __shared__ __align__(16) u16 sA[128 * 32];
  __shared__ __align__(16) u16 sB[128 * 32];
  const int tid = threadIdx.x;
  const int wave = tid >> 6, lane = tid & 63;
  const int wr = wave >> 1, wc = wave & 1;
  const int lhi = lane >> 4, llo = lane & 15;
  const int m0 = blockIdx.y * 128;
  const int n0 = blockIdx.x * 128;

  const int c0i = tid, c1i = 256 + tid;          // 16B staging chunks
  const int ar0 = c0i >> 2, ac0 = (c0i & 3) * 8;
  const int ar1 = c1i >> 2, ac1 = (c1i & 3) * 8;
  u16* lA0 = sA + c0i * 8; u16* lA1 = sA + c1i * 8;
  u16* lB0 = sB + c0i * 8; u16* lB1 = sB + c1i * 8;

  floatx4 acc[4][4];
#pragma unroll
  for (int i = 0; i < 4; ++i)
#pragma unroll
    for (int j = 0; j < 4; ++j) acc[i][j] = floatx4{0.f, 0.f, 0.f, 0.f};

  for (int t = 0; t < nblk; ++t) {
    const int bld = ga.bld[t];
    const u16* ab = ga.a[t] + (size_t)(m0base + m0) * 512;
    const u16* bb = ga.b[t] + (size_t)n0 * bld + ga.bcol[t];
    const u16* pa0 = ab + (size_t)ar0 * 512 + ac0;
    const u16* pa1 = ab + (size_t)ar1 * 512 + ac1;
    const u16* pb0 = bb + (size_t)ar0 * bld + ac0;
    const u16* pb1 = bb + (size_t)ar1 * bld + ac1;
#pragma unroll 1
    for (int kk = 0; kk < 16; ++kk) {
      const int kl = kk * 32;
      __syncthreads();                           // prior iter's LDS reads done
      gl_lds16(pa0 + kl, lA0);
      gl_lds16(pa1 + kl, lA1);
      gl_lds16(pb0 + kl, lB0);
      gl_lds16(pb1 + kl, lB1);
      __syncthreads();                           // drain global_load_lds
      short8 af[4], bf[4];
#pragma unroll
      for (int i = 0; i < 4; ++i) {
        af[i] = *(const short8*)(sA + (wr * 64 + i * 16 + llo) * 32 + lhi * 8);
        bf[i] = *(const short8*)(sB + (wc * 64 + i * 16 + llo) * 32 + lhi * 8);
      }
#pragma unroll
      for (int i = 0; i < 4; ++i)
#pragma unroll
        for (int j = 0; j < 4; ++j)
          acc[i][j] = __builtin_amdgcn_mfma_f32_16x16x32_bf16(af[i], bf[j], acc[i][j], 0, 0, 0);
    }
  }

  const int rb = m0 + wr * 64 + lhi * 4;
  const int cb = n0 + wc * 64 + llo;
#pragma unroll
  for (int i = 0; i < 4; ++i)
#pragma unroll
    for (int j = 0; j < 4; ++j)
#pragma unroll
      for (int r = 0; r < 4; ++r)
        C[(size_t)(rb + i * 16 + r) * ldc + (cb + j * 16)] = acc[i][j][r];
}

// ---- fi softmax-weighted reduction over s (chunked partials + atomics) ----
__global__ void k_fireduce(const float* __restrict__ Cfi, const float* __restrict__ a1v,
                           const float* __restrict__ c0, const int* __restrict__ seq_lens,
                           float* __restrict__ denom, float* __restrict__ cacc,
                           int sbase, int send) {
  int id = blockIdx.x * 256 + threadIdx.x;       // b*512+h
  int b = id >> 9, h = id & 511;
  int len = seq_lens[b * sl_stride(seq_lens)];
  int lim = (send < len) ? send : len;
  int s0 = sbase + blockIdx.y * 64;
  if (s0 >= lim) return;
  int s1 = (s0 + 64 < lim) ? s0 + 64 : lim;
  float a = a1v[id];
  float d = 0.f, ca = 0.f;
  for (int s = s0; s < s1; ++s) {
    size_t m = (size_t)(s * 32 + b);
    size_t ml = (size_t)((s - sbase) * 32 + b);
    float e = __expf(sigm(Cfi[ml * 512 + h] + a));
    d += e;
    ca += e * c0[m * 512 + h];
  }
  atomicAdd(&denom[id], d);
  atomicAdd(&cacc[id], ca);
}

// ---- global cell: c_g, h_g → out row S ----
__global__ void k_global(const float* __restrict__ sg0, const float* __restrict__ sg2,
                         const float* __restrict__ c0, const float* __restrict__ denom,
                         const float* __restrict__ cacc, float* __restrict__ out) {
  int id = blockIdx.x * 256 + threadIdx.x;       // 16384
  float fg = sigm(sg0[id]);
  float og = sigm(sg2[id]);
  float cg1 = c0[(size_t)HG_ROW + id];
  float dn = denom[id];
  float cg = fg * cg1 + cacc[id] / (dn > 0.f ? dn : 1.f);
  float hg = og * tanh_(cg);
  out[(size_t)HG_ROW + id] = hg;
  out[(size_t)CT_BASE + HG_ROW + id] = cg;
}

// ---- window epilogue: gates softmax-5, c_w, h_w ----
__global__ void k_epilogue(const float* __restrict__ Cch, const float* __restrict__ Vb,
                           const float* __restrict__ c0, const int* __restrict__ seq_lens,
                           float* __restrict__ out, int mbase) {
  int idx = blockIdx.x * 256 + threadIdx.x;      // chunk-local (m,h)
  int ml = idx >> 9, h = idx & 511;
  int mg = mbase + ml;
  int s = mg >> 5, b = mg & 31;
  int len = seq_lens[b * sl_stride(seq_lens)];
  float pre[7];
#pragma unroll
  for (int g = 0; g < 7; ++g)
    pre[g] = Cch[(size_t)ml * N_TOT + g * 512 + h] + Vb[(size_t)(g * 32 + b) * 512 + h];
  float i_ = sigm(pre[0]);
  float l_ = sigm(pre[1]);
  float r_ = sigm(pre[2]);
  float f_ = sigm(pre[3]);
  float sg = sigm(pre[4]);
  float o_ = sigm(pre[5]);
  float u_ = tanh_(pre[6]);
  float el = __expf(l_), ef = __expf(f_), er = __expf(r_), es = __expf(sg), ei = __expf(i_);
  float inv = 1.f / (el + ef + er + es + ei);
  float cw = 0.f;
  if (s < len) {
    float cl = (s >= 1) ? c0[(size_t)(mg - 32) * 512 + h] : 0.f;
    float cc = c0[(size_t)mg * 512 + h];
    float cr = (s + 1 < S_LEN && s + 1 < len) ? c0[(size_t)(mg + 32) * 512 + h] : 0.f;
    float cg1 = c0[(size_t)HG_ROW + b * 512 + h];
    cw = (el * cl + ef * cc + er * cr + es * cg1 + ei * u_) * inv;
  }
  float hw = o_ * tanh_(cw);
  size_t oi = (size_t)mg * 512 + h;
  out[oi] = hw;
  out[(size_t)CT_BASE + oi] = cw;
}

extern "C" void kernel_launch(void* const* d_in, const int* in_sizes, int n_in,
                              void* d_out, int out_size, void* d_ws, size_t ws_size,
                              hipStream_t stream) {
  const float* seqs = (const float*)d_in[0];
  const int* seq_lens = (const int*)d_in[1];
  const float* h0 = (const float*)d_in[2];
  const float* c0 = (const float*)d_in[3];
  const float* Ww = (const float*)d_in[4];
  const float* Wu = (const float*)d_in[5];
  const float* Wv = (const float*)d_in[6];
  const float* Wb = (const float*)d_in[7];
  const float* Sw = (const float*)d_in[8];
  const float* Su = (const float*)d_in[9];
  const float* Sb = (const float*)d_in[10];
  float* out = (float*)d_out;

  // ---- workspace layout (fixed ~49.7 MB) + adaptive C chunk ----
  char* ws = (char*)d_ws;
  size_t off = 0;
  float* denom = (float*)(ws + off); off += 16384 * 4;   // zeroed together:
  float* cacc  = (float*)(ws + off); off += 16384 * 4;   // denom, cacc, hhat
  float* hhat  = (float*)(ws + off); off += 16384 * 4;
  float* sg0  = (float*)(ws + off); off += 16384 * 4;
  float* sg2  = (float*)(ws + off); off += 16384 * 4;
  float* a1v  = (float*)(ws + off); off += 16384 * 4;
  float* Vb   = (float*)(ws + off); off += (size_t)7 * 16384 * 4;
  u16* hpad  = (u16*)(ws + off); off += (size_t)16448 * 512 * 2;   // 16.84 MB
  u16* seqsb = (u16*)(ws + off); off += (size_t)16384 * 512 * 2;   // 16.78 MB
  u16* Bcat  = (u16*)(ws + off); off += (size_t)3584 * 2048 * 2;   // 14.68 MB
  u16* Bfi   = (u16*)(ws + off); off += (size_t)512 * 512 * 2;     //  0.52 MB
  float* Cbig = (float*)(ws + off);

  size_t avail = (ws_size > off) ? (ws_size - off) : 0;
  int chunk_rows = (int)(avail / ((size_t)N_TOT * 4));
  chunk_rows = (chunk_rows / 128) * 128;
  if (chunk_rows > 4096) chunk_rows = 4096;
  if (chunk_rows < 128) chunk_rows = 128;
  int fi_rows = 7 * chunk_rows;                  // same byte budget at ldc=512
  if (fi_rows > 16384) fi_rows = 16384;

  prep_hpad<<<4112, 256, 0, stream>>>(h0, seq_lens, hpad);
  prep_seqs<<<4096, 256, 0, stream>>>(seqs, seqsb);
  prep_bcat<<<3584, 256, 0, stream>>>(Ww, Wu, Bcat);
  prep_bfi<<<128, 256, 0, stream>>>(Su, Bfi);
  k_zero<<<192, 256, 0, stream>>>(denom, 49152);          // denom+cacc+hhat
  k_hhat<<<dim3(64, 16), 256, 0, stream>>>(hpad, hhat);
  k_small<<<40960, 256, 0, stream>>>(h0, Sw, Su, Sb, Wv, Wb, hhat, sg0, sg2, a1v, Vb);

  // fi GEMM (16384 x 512) = h_w1 @ Su[1]^T, chunked over rows
  GemmSrc gfi;
  gfi.a[0] = hpad + 32 * 512; gfi.b[0] = Bfi; gfi.bld[0] = 512; gfi.bcol[0] = 0;
  for (int fb = 0; fb < 16384; fb += fi_rows) {
    int rows = (fi_rows < 16384 - fb) ? fi_rows : (16384 - fb);
    gemm_kernel<<<dim3(4, rows / 128), 256, 0, stream>>>(gfi, Cbig, 512, 1, fb);
    int sbase = fb / 32, scnt = rows / 32;
    k_fireduce<<<dim3(64, (scnt + 63) / 64), 256, 0, stream>>>(
        Cbig, a1v, c0, seq_lens, denom, cacc, sbase, sbase + scnt);
  }
  k_global<<<64, 256, 0, stream>>>(sg0, sg2, c0, denom, cacc, out);

  // main GEMM: K-blocks = {h_w1[s-1], h_w1[s], h_w1[s+1], seqs} vs Bcat col-slices
  GemmSrc gm;
  gm.a[0] = hpad;            gm.bcol[0] = 0;
  gm.a[1] = hpad + 32 * 512; gm.bcol[1] = 512;
  gm.a[2] = hpad + 64 * 512; gm.bcol[2] = 1024;
  gm.a[3] = seqsb;           gm.bcol[3] = 1536;
  for (int t = 0; t < 4; ++t) { gm.b[t] = Bcat; gm.bld[t] = 2048; }
  for (int mb = 0; mb < 16384; mb += chunk_rows) {
    int rows = (chunk_rows < 16384 - mb) ? chunk_rows : (16384 - mb);
    gemm_kernel<<<dim3(28, rows / 128), 256, 0, stream>>>(gm, Cbig, N_TOT, 4, mb);
    k_epilogue<<<rows * 2, 256, 0, stream>>>(Cbig, Vb, c0, seq_lens, out, mb);
  }
}